// Round 19
// baseline (386.164 us; speedup 1.0000x reference)
//
#include <hip/hip_runtime.h>

#define NB_HG 2048   // H*G = 32*64
#define DIM_N 128
#define DIM_D 128
#define DIM_S 256
#define PH 32        // staged rows per phase
#define BSW 128      // staged B width = block's s-window

// Numerics: golden = per-element strictly sequential ascending-d fp32 FMA over
// the SELECTED d's only (masked-out terms exact zeros). Verified bit-exact
// rounds 4-18. Compaction + phase split preserve chain order; X/B bits pass
// through LDS unmodified.
// LDS swizzle pos = idx ^ (4*(row&7)) — SQ_LDS_BANK_CONFLICT=0 verified r5-18.
// R18 post-mortem: SMEM+DS share lgkmcnt (OoO) -> full serialization; never
// mix s_load into a DS loop. R12 wall: LDS DATA PIPE 150% oversubscribed
// (4x b128/wave-iter x 16 waves/CU = 192cy vs 128). This round: wave-uniform
// 32-s window per wave -> B reads are same-address broadcasts (m136: free),
// X read is one ds_read_b64/lane. LDS demand ~88cy/128 -> VALU unthrottled.

__global__ void transpose_proj_kernel(const float* __restrict__ proj,
                                      float* __restrict__ projT)
{
    const int d = blockIdx.x;                      // 128
    const int s = threadIdx.x;                     // 256
    projT[d * DIM_S + s] = proj[s * DIM_D + d];    // coalesced write
}

template<bool TP>
__global__ __launch_bounds__(256)
void qjl_sketch_kernel(const float* __restrict__ data,
                       const float* __restrict__ mask,
                       const float* __restrict__ pmat,   // TP ? projT[d][s] : proj[s][d]
                       int* __restrict__ out)
{
    __shared__ float Xt[PH * DIM_N];               // 16 KB
    __shared__ float Bs[PH * BSW];                 // 16 KB
    __shared__ int   cidx[DIM_D];
    __shared__ int   wcnt[2];

    const int type = blockIdx.x;   // 0: inlier s<128, 1: inlier s>=128, 2: outlier s<128
    const int hg   = blockIdx.y;
    const int tid  = threadIdx.x;
    const int l    = tid & 63;                     // lane
    const int wv   = tid >> 6;                     // wave 0..3

    // ---------- build compacted ascending list of selected d's ----------
    bool sel = false; int pos = 0, w = 0;
    if (tid < 128) {                               // waves 0,1 only (whole waves)
        const float m = mask[hg * DIM_D + tid];    // exactly 0.0f or 1.0f
        sel = (type == 2) ? (m != 0.0f) : (m == 0.0f);
        const unsigned long long bal = __ballot(sel);
        w = tid >> 6;
        if (l == 0) wcnt[w] = __popcll(bal);
        pos = __popcll(bal & ((1ull << l) - 1ull));
    }
    __syncthreads();
    if (sel) cidx[pos + (w ? wcnt[0] : 0)] = tid;  // tid == d, ascending preserved
    __syncthreads();
    const int K = wcnt[0] + wcnt[1];               // uniform across block

    const int sbase = (type == 1) ? 128 : 0;

    // compute mapping: wave wv owns s-window [32*wv, 32*wv+32) (wave-uniform);
    // lane l owns logical n = 2l, 2l+1 -> chunk l>>1, in-chunk float 2*(l&1)
    const int chunk = l >> 1;
    const int half2 = 2 * (l & 1);
    const int swv   = 32 * wv;

    float acc[32][2];                              // [s_local][n-slot]
    #pragma unroll
    for (int j = 0; j < 32; ++j) { acc[j][0] = 0.0f; acc[j][1] = 0.0f; }

    // staging thread mapping (constant across phases)
    const int cl_s  = tid & 31;                    // LDS row this thread stages
    const int nh    = tid >> 5;                    // 0..7: 16-wide slice
    const int pcs_s = 4 * (cl_s & 7);
    float* xrow = &Xt[cl_s * DIM_N];
    float* brow = &Bs[cl_s * BSW];

    auto STAGE = [&](int base, int kp) {
        if (cl_s < kp) {
            const int dg = cidx[base + cl_s];
            const float* Xs = data + (size_t)hg * (DIM_N * DIM_D) + dg;
            #pragma unroll
            for (int g = 0; g < 4; ++g) {
                const int n0 = nh * 16 + g * 4;
                float4 v;
                v.x = Xs[(size_t)(n0 + 0) * DIM_D];
                v.y = Xs[(size_t)(n0 + 1) * DIM_D];
                v.z = Xs[(size_t)(n0 + 2) * DIM_D];
                v.w = Xs[(size_t)(n0 + 3) * DIM_D];
                *reinterpret_cast<float4*>(&xrow[n0 ^ pcs_s]) = v;
            }
            if (TP) {
                const float* Ps = pmat + (size_t)dg * DIM_S + sbase;
                #pragma unroll
                for (int g = 0; g < 4; ++g) {
                    const int s0l = nh * 16 + g * 4;
                    const float4 b = *reinterpret_cast<const float4*>(Ps + s0l);
                    *reinterpret_cast<float4*>(&brow[s0l ^ pcs_s]) = b;
                }
            } else {
                #pragma unroll
                for (int g = 0; g < 4; ++g) {
                    const int s0l = nh * 16 + g * 4;
                    float4 b;
                    b.x = pmat[(size_t)(sbase + s0l + 0) * DIM_D + dg];
                    b.y = pmat[(size_t)(sbase + s0l + 1) * DIM_D + dg];
                    b.z = pmat[(size_t)(sbase + s0l + 2) * DIM_D + dg];
                    b.w = pmat[(size_t)(sbase + s0l + 3) * DIM_D + dg];
                    *reinterpret_cast<float4*>(&brow[s0l ^ pcs_s]) = b;
                }
            }
        }
    };

    auto COMPUTE = [&](int kp) {
        #pragma unroll 8
        for (int cl = 0; cl < kp; ++cl) {          // ascending selected d
            const int swz = cl & 7;                // compile-time under unroll
            // B: 32 floats via 8 wave-uniform ds_read_b128 (broadcast, free)
            float b[32];
            #pragma unroll
            for (int k = 0; k < 8; ++k) {
                const int p = (swv + 4 * k) ^ (4 * swz);
                const float4 bb = *reinterpret_cast<const float4*>(&Bs[cl * BSW + p]);
                b[4*k+0] = bb.x; b[4*k+1] = bb.y; b[4*k+2] = bb.z; b[4*k+3] = bb.w;
            }
            // X: lane's 2 n via one ds_read_b64 (contiguous 512B/wave)
            const int phys = ((chunk ^ swz) << 2) + half2;
            const float2 q = *reinterpret_cast<const float2*>(&Xt[cl * DIM_N + phys]);

            #pragma unroll
            for (int j = 0; j < 32; ++j) {
                acc[j][0] = fmaf(b[j], q.x, acc[j][0]);   // serial dep: order fixed
                acc[j][1] = fmaf(b[j], q.y, acc[j][1]);
            }
        }
    };

    for (int base = 0; base < K; base += PH) {     // K uniform -> no barrier divergence
        const int kp = (K - base < PH) ? (K - base) : PH;
        if (base) __syncthreads();                 // prior phase's reads done
        STAGE(base, kp);
        __syncthreads();
        COMPUTE(kp);
    }

    // ---------- sign-pack (bit = s > 0) and store as int32 ----------
    // byte index within the 128-s window: 4*wv + k (k=0..3), s_local = 8k+bit
    const size_t inl_total = (size_t)NB_HG * DIM_N * 32;   // 8388608
    const size_t orow = (size_t)hg * DIM_N;
    #pragma unroll
    for (int i = 0; i < 2; ++i) {
        const int n = 2 * l + i;
        #pragma unroll
        for (int k = 0; k < 4; ++k) {
            int v = 0;
            #pragma unroll
            for (int bit = 0; bit < 8; ++bit)
                if (acc[8 * k + bit][i] > 0.0f) v |= (1 << bit);
            size_t idx;
            if (type == 2)
                idx = inl_total + (orow + n) * 16 + 4 * wv + k;
            else
                idx = (orow + n) * 32 + (type == 1 ? 16 : 0) + 4 * wv + k;
            out[idx] = v;
        }
    }
}

extern "C" void kernel_launch(void* const* d_in, const int* in_sizes, int n_in,
                              void* d_out, int out_size, void* d_ws, size_t ws_size,
                              hipStream_t stream) {
    const float* data = (const float*)d_in[0];   // (1,32,64,128,128) fp32
    const float* mask = (const float*)d_in[1];   // (1,32,64,128) fp32, values {0,1}
    const float* proj = (const float*)d_in[2];   // (256,128) fp32
    int* out = (int*)d_out;                      // 8388608 inlier + 4194304 outlier int32

    dim3 grid(3, NB_HG);
    const size_t tp_bytes = (size_t)DIM_D * DIM_S * sizeof(float);   // 128 KB
    if (ws_size >= tp_bytes) {
        float* projT = (float*)d_ws;
        transpose_proj_kernel<<<DIM_D, DIM_S, 0, stream>>>(proj, projT);
        qjl_sketch_kernel<true><<<grid, 256, 0, stream>>>(data, mask, projT, out);
    } else {
        qjl_sketch_kernel<false><<<grid, 256, 0, stream>>>(data, mask, proj, out);
    }
}

// Round 20
// 189.040 us; speedup vs baseline: 2.0428x; 2.0428x over previous
//
#include <hip/hip_runtime.h>

#define NB_HG 2048   // H*G = 32*64
#define DIM_N 128
#define DIM_D 128
#define DIM_S 256
#define PH 32        // staged rows per phase
#define BSW 128      // staged B width = block's s-window

// FINAL (revert to round-12 best: 187 us, absmax 0).
// Numerics: golden = per-element strictly sequential ascending-d fp32 FMA over
// the SELECTED d's only (masked-out terms exact zeros; fmaf(b,±0,acc)==acc).
// Verified bit-exact rounds 4-19. Mask compaction halves FMA work; phase split
// preserves chain order; X/B bits pass through LDS unmodified.
// LDS swizzle pos = idx ^ (4*(row&7)) — SQ_LDS_BANK_CONFLICT=0 verified r5-19.
// Structural ceiling (r13-r19 exploration): LDS data pipe at ~100-150% of
// capacity for the register-feasible 8x8 tile (4x ds_read_b128 / 64 FMA);
// larger tiles need >=256 acc VGPRs; SMEM b serializes lgkmcnt (r18);
// broadcast b costs more pipe slots (r19); async staging doesn't move dur
// (r15); at 34.5 T-FMA/s vs m07's ~51 T measured ceiling with mandatory
// sequential-chain numerics, this is the practical floor for this op.

__global__ void transpose_proj_kernel(const float* __restrict__ proj,
                                      float* __restrict__ projT)
{
    const int d = blockIdx.x;                      // 128
    const int s = threadIdx.x;                     // 256
    projT[d * DIM_S + s] = proj[s * DIM_D + d];    // coalesced write
}

template<bool TP>
__global__ __launch_bounds__(256)
void qjl_sketch_kernel(const float* __restrict__ data,
                       const float* __restrict__ mask,
                       const float* __restrict__ pmat,   // TP ? projT[d][s] : proj[s][d]
                       int* __restrict__ out)
{
    __shared__ float Xt[PH * DIM_N];               // 16 KB
    __shared__ float Bs[PH * BSW];                 // 16 KB
    __shared__ int   cidx[DIM_D];
    __shared__ int   wcnt[2];

    const int type = blockIdx.x;   // 0: inlier s<128, 1: inlier s>=128, 2: outlier s<128
    const int hg   = blockIdx.y;
    const int tid  = threadIdx.x;

    // ---------- build compacted ascending list of selected d's ----------
    bool sel = false; int pos = 0, w = 0;
    if (tid < 128) {                               // waves 0,1 only (whole waves)
        const float m = mask[hg * DIM_D + tid];    // exactly 0.0f or 1.0f
        sel = (type == 2) ? (m != 0.0f) : (m == 0.0f);
        const unsigned long long bal = __ballot(sel);
        const int lane = tid & 63;
        w = tid >> 6;
        if (lane == 0) wcnt[w] = __popcll(bal);
        pos = __popcll(bal & ((1ull << lane) - 1ull));
    }
    __syncthreads();
    if (sel) cidx[pos + (w ? wcnt[0] : 0)] = tid;  // tid == d, ascending preserved
    __syncthreads();
    const int K = wcnt[0] + wcnt[1];               // uniform across block

    const int tn = tid & 15;                       // 16 n-groups
    const int ts = tid >> 4;                       // 16 s-groups
    const int C0 = 4 * tn;
    const int sl = ts * 8;                         // s_local base
    const int sbase = (type == 1) ? 128 : 0;

    float acc[8][8];                               // [j: s-bit][i: n-slot]
    #pragma unroll
    for (int j = 0; j < 8; ++j)
        #pragma unroll
        for (int i = 0; i < 8; ++i) acc[j][i] = 0.0f;

    // staging thread mapping (constant across phases)
    const int cl_s  = tid & 31;                    // LDS row this thread stages
    const int nh    = tid >> 5;                    // 0..7: 16-wide slice
    const int pcs_s = 4 * (cl_s & 7);
    float* xrow = &Xt[cl_s * DIM_N];
    float* brow = &Bs[cl_s * BSW];

    auto STAGE = [&](int base, int kp) {
        if (cl_s < kp) {
            const int dg = cidx[base + cl_s];
            const float* Xs = data + (size_t)hg * (DIM_N * DIM_D) + dg;
            #pragma unroll
            for (int g = 0; g < 4; ++g) {
                const int n0 = nh * 16 + g * 4;
                float4 v;
                v.x = Xs[(size_t)(n0 + 0) * DIM_D];
                v.y = Xs[(size_t)(n0 + 1) * DIM_D];
                v.z = Xs[(size_t)(n0 + 2) * DIM_D];
                v.w = Xs[(size_t)(n0 + 3) * DIM_D];
                *reinterpret_cast<float4*>(&xrow[n0 ^ pcs_s]) = v;
            }
            if (TP) {
                const float* Ps = pmat + (size_t)dg * DIM_S + sbase;
                #pragma unroll
                for (int g = 0; g < 4; ++g) {
                    const int s0l = nh * 16 + g * 4;
                    const float4 b = *reinterpret_cast<const float4*>(Ps + s0l);
                    *reinterpret_cast<float4*>(&brow[s0l ^ pcs_s]) = b;
                }
            } else {
                #pragma unroll
                for (int g = 0; g < 4; ++g) {
                    const int s0l = nh * 16 + g * 4;
                    float4 b;
                    b.x = pmat[(size_t)(sbase + s0l + 0) * DIM_D + dg];
                    b.y = pmat[(size_t)(sbase + s0l + 1) * DIM_D + dg];
                    b.z = pmat[(size_t)(sbase + s0l + 2) * DIM_D + dg];
                    b.w = pmat[(size_t)(sbase + s0l + 3) * DIM_D + dg];
                    *reinterpret_cast<float4*>(&brow[s0l ^ pcs_s]) = b;
                }
            }
        }
    };

    auto COMPUTE = [&](int kp) {
        #pragma unroll 8
        for (int cl = 0; cl < kp; ++cl) {          // ascending selected d
            const int pcs = 4 * (cl & 7);          // compile-time under unroll
            const int pA  = sl ^ pcs;              // holds s_local sl..sl+3
            const float4 bA = *reinterpret_cast<const float4*>(&Bs[cl * BSW + pA]);
            const float4 bB = *reinterpret_cast<const float4*>(&Bs[cl * BSW + (pA ^ 4)]);
            const int P = C0 ^ pcs;
            const float4 q0 = *reinterpret_cast<const float4*>(&Xt[cl * DIM_N + P]);
            const float4 q1 = *reinterpret_cast<const float4*>(&Xt[cl * DIM_N + P + 64]);
            const float bv[8] = {bA.x, bA.y, bA.z, bA.w, bB.x, bB.y, bB.z, bB.w};

            #pragma unroll
            for (int j = 0; j < 8; ++j) {
                acc[j][0] = fmaf(bv[j], q0.x, acc[j][0]);   // serial dep: order fixed
                acc[j][1] = fmaf(bv[j], q0.y, acc[j][1]);
                acc[j][2] = fmaf(bv[j], q0.z, acc[j][2]);
                acc[j][3] = fmaf(bv[j], q0.w, acc[j][3]);
                acc[j][4] = fmaf(bv[j], q1.x, acc[j][4]);
                acc[j][5] = fmaf(bv[j], q1.y, acc[j][5]);
                acc[j][6] = fmaf(bv[j], q1.z, acc[j][6]);
                acc[j][7] = fmaf(bv[j], q1.w, acc[j][7]);
            }
        }
    };

    for (int base = 0; base < K; base += PH) {     // K uniform -> no barrier divergence
        const int kp = (K - base < PH) ? (K - base) : PH;
        if (base) __syncthreads();                 // prior phase's reads done
        STAGE(base, kp);
        __syncthreads();
        COMPUTE(kp);
    }

    // ---------- sign-pack (bit j = sbase+sl+j > 0) and store as int32 ----------
    const size_t inl_total = (size_t)NB_HG * DIM_N * 32;   // 8388608
    #pragma unroll
    for (int i = 0; i < 8; ++i) {
        int byte = 0;
        #pragma unroll
        for (int j = 0; j < 8; ++j)
            if (acc[j][i] > 0.0f) byte |= (1 << j);
        const int n = (i < 4) ? (C0 + i) : (64 + C0 + (i - 4));
        size_t idx;
        if (type == 2)
            idx = inl_total + ((size_t)hg * DIM_N + n) * 16 + ts;
        else
            idx = ((size_t)hg * DIM_N + n) * 32 + (type == 1 ? 16 : 0) + ts;
        out[idx] = byte;
    }
}

extern "C" void kernel_launch(void* const* d_in, const int* in_sizes, int n_in,
                              void* d_out, int out_size, void* d_ws, size_t ws_size,
                              hipStream_t stream) {
    const float* data = (const float*)d_in[0];   // (1,32,64,128,128) fp32
    const float* mask = (const float*)d_in[1];   // (1,32,64,128) fp32, values {0,1}
    const float* proj = (const float*)d_in[2];   // (256,128) fp32
    int* out = (int*)d_out;                      // 8388608 inlier + 4194304 outlier int32

    dim3 grid(3, NB_HG);
    const size_t tp_bytes = (size_t)DIM_D * DIM_S * sizeof(float);   // 128 KB
    if (ws_size >= tp_bytes) {
        float* projT = (float*)d_ws;
        transpose_proj_kernel<<<DIM_D, DIM_S, 0, stream>>>(proj, projT);
        qjl_sketch_kernel<true><<<grid, 256, 0, stream>>>(data, mask, projT, out);
    } else {
        qjl_sketch_kernel<false><<<grid, 256, 0, stream>>>(data, mask, proj, out);
    }
}